// Round 8
// baseline (486874.316 us; speedup 1.0000x reference)
//
#include <hip/hip_runtime.h>
#include <math.h>

// Problem constants
#define NN 1024
#define MM 64
#define CC 512
#define LL 64
#define TT 8192
#define EPSF 1e-16f

typedef float vf4 __attribute__((ext_vector_type(4)));   // real vector type -> v_pk_fma_f32

// Flat output offsets (return order: seq_out, ww_h, rw_h, a_h, r_h)
#define OFF_SEQ 0
#define OFF_WW  (TT*LL)
#define OFF_RW  (OFF_WW + TT*NN)
#define OFF_A   (OFF_RW + TT*NN)
#define OFF_R   (OFF_A + TT*MM)

// d_ws float offsets
#define WSF_PRE   0
#define WSF_M     (TT*CC)              // 8*1024 vf4 = 32768 floats (M cols 32..63)
#define WSF_WCAT  (WSF_M + 32768)      // 512*272 packed [Ww | Wr | 0pad]

__device__ __forceinline__ float sigmoid_f(float x) { return 1.0f / (1.0f + __expf(-x)); }
__device__ __forceinline__ float softplus_f(float x) { return (x > 15.0f) ? x : __logf(1.0f + __expf(x)); }
__device__ __forceinline__ float tanh_f(float x) { float e = __expf(2.0f * x); return 1.0f - 2.0f / (e + 1.0f); }
__device__ __forceinline__ float pow_f(float b, float g) { return __expf(g * __logf(b)); }  // b >= 0
__device__ __forceinline__ int bitrev4(int l) {
    return ((l & 1) << 3) | ((l & 2) << 1) | ((l & 4) >> 1) | ((l & 8) >> 3);
}

// Kernel 1: pre[t][j] = sum_i seq[t][i] * Wc[i][j] + bc[j]
__global__ void pre_kernel(const float* __restrict__ seq, const float* __restrict__ Wc,
                           const float* __restrict__ bc, float* __restrict__ pre) {
    int gid = blockIdx.x * blockDim.x + threadIdx.x;
    int t = gid >> 9;
    int j = gid & 511;
    if (t >= TT) return;
    const float* s = seq + t * LL;
    float acc = bc[j];
    #pragma unroll 8
    for (int i = 0; i < LL; ++i) acc += s[i] * Wc[i * CC + j];
    pre[gid] = acc;
}

// Kernel 1b: Wcat[512][272] = [Ww (198 cols) | Wr (70 cols) | 4 zero cols]
__global__ void pack_kernel(const float* __restrict__ Ww, const float* __restrict__ Wr,
                            float* __restrict__ Wcat) {
    int gid = blockIdx.x * 256 + threadIdx.x;
    if (gid >= 512 * 272) return;
    int r = gid / 272, c = gid - r * 272;
    float v = 0.0f;
    if (c < 198) v = Ww[r * 198 + c];
    else if (c < 268) v = Wr[r * 70 + (c - 198)];
    Wcat[gid] = v;
}

// Persistent single workgroup (round-7 verified structure: M cols 0-31 in 32 VGPRs,
// cols 32-63 in ws_m vf4 private slots; fp32 throughout the recurrence).
// Round-8: (1) Wcat rows 0-95 (104 KB) cached in LDS -> phase C L2 stream 557->453 KB,
// LDS reads ride the DS pipe (overlaps VMEM). (2) ext_vector vf4 math in the hot
// inner loops -> packed v_pk_fma_f32 halves FMA issue slots. Per-component accumulation
// order preserved -> numerics identical to round 7.
__global__ __launch_bounds__(1024)
void ntm_kernel(
    const float* __restrict__ pre,   // [TT][CC]
    const float* __restrict__ Wc,    // [128][512]
    const float* __restrict__ Wcat,  // [512][272] packed Ww|Wr
    const float* __restrict__ br,    // [70]
    const float* __restrict__ bw,    // [198]
    const float* __restrict__ Wo,    // [64][64]
    const float* __restrict__ bo,    // [64]
    float* __restrict__ out,
    vf4* __restrict__ ws_m)          // [8][1024] private M cols 32..63
{
    __shared__ __align__(16) vf4   sh_wcat[96 * 68];  // Wcat rows 0..95 (104.4 KB)
    __shared__ __align__(16) float sh_part[4096];     // A: 8x512 ; C: 8x272
    __shared__ __align__(16) float sh_h[CC];
    __shared__ __align__(16) float sh_kw[MM];
    __shared__ __align__(16) float sh_kr[MM];
    __shared__ __align__(16) float sh_e[MM];
    __shared__ __align__(16) float sh_a[MM];
    __shared__ __align__(16) float sh_scal[16];
    __shared__ __align__(16) float sh_evbuf[NN];
    __shared__ __align__(16) float sh_wpbuf[NN];
    __shared__ __align__(16) float red[4][16];
    __shared__ __align__(16) float wmat[16][MM];
    __shared__ __align__(16) float sh_r[MM];
    __shared__ __align__(16) float sh_Wo[MM * LL];
    __shared__ __align__(16) float sh_bo[LL];
    __shared__ __align__(16) float sh_bw[200];
    __shared__ __align__(16) float sh_br[72];
    __shared__ __align__(16) float sh_pren[CC];       // prefetched pre[t+1]

    const int tid  = threadIdx.x;
    const int lane = tid & 63;
    const int wv   = tid >> 6;

    // ---- preload constants into LDS, init state ----
    for (int i = tid; i < MM * LL; i += NN) sh_Wo[i] = Wo[i];
    {
        const vf4* wc4 = (const vf4*)Wcat;
        for (int i = tid; i < 96 * 68; i += NN) sh_wcat[i] = wc4[i];
    }
    if (tid < LL)  sh_bo[tid] = bo[tid];
    if (tid < 198) sh_bw[tid] = bw[tid];
    if (tid < 70)  sh_br[tid] = br[tid];
    if (tid < MM)  sh_r[tid] = 1e-6f;
    if (tid < CC)  sh_pren[tid] = pre[tid];

    float Mlo[32];
    #pragma unroll
    for (int j = 0; j < 32; ++j) Mlo[j] = 1e-6f;
    vf4 mh[8];
    const vf4 minit = {1e-6f, 1e-6f, 1e-6f, 1e-6f};
    #pragma unroll
    for (int k = 0; k < 8; ++k) {
        mh[k] = minit;
        ws_m[k * NN + tid] = mh[k];
    }
    float rown = sqrtf(64.0f * 1e-12f);
    float wwprev = (tid == NN / 2) ? 1.0f : 0.0f;
    float rwprev = wwprev;
    __syncthreads();

    for (int t = 0; t < TT; ++t) {
        // ===== A: h-partials, vf4 col-groups. thread=(g:128 col-groups, q:8 row-chunks) =====
        {
            int g = tid & 127, q = tid >> 7;          // cols 4g..4g+3, rows 8q..8q+7 of Wc2
            const vf4* wbase = (const vf4*)(Wc + (64 + q * 8) * CC) + g;
            vf4 acc = {0.0f, 0.0f, 0.0f, 0.0f};
            #pragma unroll
            for (int i = 0; i < 8; ++i) {
                float rv = sh_r[q * 8 + i];
                acc += wbase[i * 128] * rv;           // packed fma
            }
            ((vf4*)sh_part)[q * 128 + g] = acc;       // sh_part[q*512 + 4g]
        }
        __syncthreads();  // 1
        // ===== B: h = tanh(pre + 8 partials) =====
        if (tid < CC) {
            float p0 = sh_part[tid]          + sh_part[512 + tid];
            float p1 = sh_part[1024 + tid]   + sh_part[1536 + tid];
            float p2 = sh_part[2048 + tid]   + sh_part[2560 + tid];
            float p3 = sh_part[3072 + tid]   + sh_part[3584 + tid];
            float v = sh_pren[tid] + ((p0 + p1) + (p2 + p3));
            sh_h[tid] = tanh_f(v);
        }
        __syncthreads();  // 2
        // ===== C: ow/orr partials; rows 0-95 from LDS, 96-511 from L2. 544 threads =====
        if (tid < 544) {
            int g = tid % 68, q = tid / 68;           // cols 4g..4g+3, rows 64q..64q+63
            const vf4* wbase = (const vf4*)Wcat + g;
            vf4 acc = {0.0f, 0.0f, 0.0f, 0.0f};
            int base = q * 64;
            int nl = (q == 0) ? 64 : ((q == 1) ? 32 : 0);   // rows resident in LDS
            #pragma unroll 8
            for (int i = 0; i < nl; ++i) {
                float hv = sh_h[base + i];
                acc += sh_wcat[(base + i) * 68 + g] * hv;
            }
            #pragma unroll 8
            for (int i = nl; i < 64; ++i) {
                float hv = sh_h[base + i];
                acc += wbase[(base + i) * 68] * hv;
            }
            ((vf4*)sh_part)[q * 68 + g] = acc;        // sh_part[q*272 + 4g]
        }
        __syncthreads();  // 3
        // ===== D: head transforms, ow folded inline from 8 partials (+ pre prefetch) =====
        #define OWV(c) ( (((sh_part[(c)] + sh_part[272 + (c)]) + (sh_part[544 + (c)] + sh_part[816 + (c)])) \
                        + ((sh_part[1088 + (c)] + sh_part[1360 + (c)]) + (sh_part[1632 + (c)] + sh_part[1904 + (c)]))) \
                        + ((c) < 198 ? sh_bw[(c)] : sh_br[(c) - 198]) )
        if (wv == 0) {
            float v = tanh_f(OWV(lane));
            sh_kw[lane] = v;
            float s2 = v * v;
            #pragma unroll
            for (int m = 1; m < 64; m <<= 1) s2 += __shfl_xor(s2, m, 64);
            if (lane == 0) sh_scal[6] = sqrtf(s2);
        } else if (wv == 1) {
            float v = tanh_f(OWV(198 + lane));
            sh_kr[lane] = v;
            float s2 = v * v;
            #pragma unroll
            for (int m = 1; m < 64; m <<= 1) s2 += __shfl_xor(s2, m, 64);
            if (lane == 0) sh_scal[14] = sqrtf(s2);
        } else if (wv == 2) {
            sh_e[lane] = sigmoid_f(OWV(70 + lane));
        } else if (wv == 3) {
            float v = tanh_f(OWV(134 + lane));
            sh_a[lane] = v;
            out[OFF_A + t * MM + lane] = v;
        } else if (wv == 4) {
            if (lane == 0) {
                sh_scal[0] = softplus_f(OWV(64));
                sh_scal[1] = sigmoid_f(OWV(65));
                float x0 = OWV(66), x1 = OWV(67), x2 = OWV(68);
                float mx = fmaxf(x0, fmaxf(x1, x2));
                float e0 = __expf(x0 - mx), e1 = __expf(x1 - mx), e2 = __expf(x2 - mx);
                float ss = e0 + e1 + e2;
                sh_scal[2] = e0 / ss; sh_scal[3] = e1 / ss; sh_scal[4] = e2 / ss;
                sh_scal[5] = 1.0f + softplus_f(OWV(69));
            }
        } else if (wv == 5) {
            if (lane == 0) {
                sh_scal[8] = softplus_f(OWV(198 + 64));
                sh_scal[9] = sigmoid_f(OWV(198 + 65));
                float x0 = OWV(198 + 66), x1 = OWV(198 + 67), x2 = OWV(198 + 68);
                float mx = fmaxf(x0, fmaxf(x1, x2));
                float e0 = __expf(x0 - mx), e1 = __expf(x1 - mx), e2 = __expf(x2 - mx);
                float ss = e0 + e1 + e2;
                sh_scal[10] = e0 / ss; sh_scal[11] = e1 / ss; sh_scal[12] = e2 / ss;
                sh_scal[13] = 1.0f + softplus_f(OWV(198 + 69));
            }
        } else if (wv >= 6 && wv < 14) {     // prefetch pre[t+1] into LDS (512 idle threads)
            if (t + 1 < TT) sh_pren[tid - 384] = pre[(t + 1) * CC + (tid - 384)];
        }
        #undef OWV
        __syncthreads();  // 4

        // ===== E: write-head dot + ev =====
        float betaW = sh_scal[0], gW = sh_scal[1];
        float s0W = sh_scal[2], s1W = sh_scal[3], s2W = sh_scal[4];
        float gamW = sh_scal[5], knW = sh_scal[6];
        {
            #pragma unroll
            for (int k = 0; k < 8; ++k) mh[k] = ws_m[k * NN + tid];
            const vf4* k4 = (const vf4*)sh_kw;
            const vf4* Mlo4 = (const vf4*)Mlo;
            vf4 dv = {0.0f, 0.0f, 0.0f, 0.0f};
            #pragma unroll
            for (int j4 = 0; j4 < 8; ++j4) dv += Mlo4[j4] * k4[j4];
            #pragma unroll
            for (int k8 = 0; k8 < 8; ++k8) dv += mh[k8] * k4[8 + k8];
            float dot = (dv.x + dv.y) + (dv.z + dv.w);
            float sim = dot / (rown * knW + EPSF);
            float ev = __expf(betaW * sim);
            sh_evbuf[tid] = ev;
            sh_wpbuf[tid] = wwprev;
            float s = ev;
            #pragma unroll
            for (int m = 1; m < 64; m <<= 1) s += __shfl_xor(s, m, 64);
            if (lane == 0) red[0][wv] = s;
        }
        __syncthreads();  // 5
        // ===== F: conv + sharpen (write) =====
        float wshW;
        {
            const vf4* rp = (const vf4*)red[0];
            vf4 sv = rp[0] + rp[1] + rp[2] + rp[3];
            float Sev = (sv.x + sv.y) + (sv.z + sv.w);
            int tm1 = (tid + NN - 1) & (NN - 1), tp1 = (tid + 1) & (NN - 1);
            float cEV = s0W * sh_evbuf[tm1] + s1W * sh_evbuf[tid] + s2W * sh_evbuf[tp1];
            float cWP = s0W * sh_wpbuf[tm1] + s1W * sh_wpbuf[tid] + s2W * sh_wpbuf[tp1];
            float ws = (gW / Sev) * cEV + (1.0f - gW) * cWP;
            wshW = pow_f(ws, gamW);
            float s = wshW;
            #pragma unroll
            for (int m = 1; m < 64; m <<= 1) s += __shfl_xor(s, m, 64);
            if (lane == 0) red[1][wv] = s;
        }
        __syncthreads();  // 6
        // ===== G: normalize wwn; M update + norm (vf4 packed) =====
        {
            const vf4* rp = (const vf4*)red[1];
            vf4 sv = rp[0] + rp[1] + rp[2] + rp[3];
            float Swsh = (sv.x + sv.y) + (sv.z + sv.w);
            float wwn = wshW / (Swsh + EPSF);
            out[OFF_WW + t * NN + tid] = wwn;
            wwprev = wwn;
            const vf4* e4 = (const vf4*)sh_e;
            const vf4* a4 = (const vf4*)sh_a;
            vf4* Mlo4 = (vf4*)Mlo;
            const vf4 one = {1.0f, 1.0f, 1.0f, 1.0f};
            vf4 nacc = {0.0f, 0.0f, 0.0f, 0.0f};
            #pragma unroll
            for (int j4 = 0; j4 < 8; ++j4) {
                vf4 m = Mlo4[j4];
                m = m * (one - e4[j4] * wwn) + a4[j4] * wwn;
                Mlo4[j4] = m;
                nacc += m * m;
            }
            #pragma unroll
            for (int k = 0; k < 8; ++k) {
                vf4 m = mh[k];
                m = m * (one - e4[8 + k] * wwn) + a4[8 + k] * wwn;
                mh[k] = m;
                ws_m[k * NN + tid] = m;
                nacc += m * m;
            }
            rown = sqrtf((nacc.x + nacc.y) + (nacc.z + nacc.w));
        }

        // ===== H: read-head dot + ev =====
        float betaR = sh_scal[8], gR = sh_scal[9];
        float s0R = sh_scal[10], s1R = sh_scal[11], s2R = sh_scal[12];
        float gamR = sh_scal[13], knR = sh_scal[14];
        {
            const vf4* k4 = (const vf4*)sh_kr;
            const vf4* Mlo4 = (const vf4*)Mlo;
            vf4 dv = {0.0f, 0.0f, 0.0f, 0.0f};
            #pragma unroll
            for (int j4 = 0; j4 < 8; ++j4) dv += Mlo4[j4] * k4[j4];
            #pragma unroll
            for (int k8 = 0; k8 < 8; ++k8) dv += mh[k8] * k4[8 + k8];
            float dot = (dv.x + dv.y) + (dv.z + dv.w);
            float sim = dot / (rown * knR + EPSF);
            float ev = __expf(betaR * sim);
            sh_evbuf[tid] = ev;
            sh_wpbuf[tid] = rwprev;
            float s = ev;
            #pragma unroll
            for (int m = 1; m < 64; m <<= 1) s += __shfl_xor(s, m, 64);
            if (lane == 0) red[2][wv] = s;
        }
        __syncthreads();  // 7
        // ===== I: conv + sharpen (read); transpose partials =====
        float wshR;
        {
            const vf4* rp = (const vf4*)red[2];
            vf4 sv = rp[0] + rp[1] + rp[2] + rp[3];
            float Sev = (sv.x + sv.y) + (sv.z + sv.w);
            int tm1 = (tid + NN - 1) & (NN - 1), tp1 = (tid + 1) & (NN - 1);
            float cEV = s0R * sh_evbuf[tm1] + s1R * sh_evbuf[tid] + s2R * sh_evbuf[tp1];
            float cWP = s0R * sh_wpbuf[tm1] + s1R * sh_wpbuf[tid] + s2R * sh_wpbuf[tp1];
            float ws = (gR / Sev) * cEV + (1.0f - gR) * cWP;
            wshR = pow_f(ws, gamR);
            float s = wshR;
            #pragma unroll
            for (int m = 1; m < 64; m <<= 1) s += __shfl_xor(s, m, 64);
            if (lane == 0) red[3][wv] = s;
            #pragma unroll
            for (int chunk = 0; chunk < 4; ++chunk) {
                const int cb = chunk * 16;
                float v[16];
                if (chunk < 2) {
                    #pragma unroll
                    for (int i = 0; i < 16; ++i) v[i] = wshR * Mlo[chunk * 16 + i];
                } else {
                    #pragma unroll
                    for (int k = 0; k < 4; ++k) {
                        vf4 m = mh[(chunk - 2) * 4 + k];
                        v[4*k]   = wshR * m.x;
                        v[4*k+1] = wshR * m.y;
                        v[4*k+2] = wshR * m.z;
                        v[4*k+3] = wshR * m.w;
                    }
                }
                #pragma unroll
                for (int st = 0; st < 4; ++st) {
                    const int m = 1 << st;
                    const int hs = 8 >> st;
                    bool hi = (lane & m) != 0;
                    #pragma unroll
                    for (int i = 0; i < 8; ++i) {
                        if (i < hs) {
                            float send = hi ? v[i] : v[i + hs];
                            float recv = __shfl_xor(send, m, 64);
                            float keep = hi ? v[i + hs] : v[i];
                            v[i] = keep + recv;
                        }
                    }
                }
                float v0 = v[0];
                v0 += __shfl_xor(v0, 16, 64);
                v0 += __shfl_xor(v0, 32, 64);
                if (lane < 16) wmat[wv][cb + bitrev4(lane)] = v0;
            }
        }
        __syncthreads();  // 8
        // ===== J: normalize rwn + finalize =====
        {
            const vf4* rp = (const vf4*)red[3];
            vf4 sv = rp[0] + rp[1] + rp[2] + rp[3];
            float Swsh = (sv.x + sv.y) + (sv.z + sv.w);
            float inv = 1.0f / (Swsh + EPSF);
            float rwn = wshR * inv;
            out[OFF_RW + t * NN + tid] = rwn;
            rwprev = rwn;
            if (tid < MM) {
                float rv = 0.0f;
                #pragma unroll
                for (int w = 0; w < 16; ++w) rv += wmat[w][tid];
                rv *= inv;
                sh_r[tid] = rv;
                out[OFF_R + t * MM + tid] = rv;
            }
        }
        __syncthreads();  // 9
        // ===== K: output projection =====
        if (tid < LL) {
            const float* rr = sh_r;
            float a0 = 0.0f, a1 = 0.0f;
            #pragma unroll
            for (int i = 0; i < 64; i += 2) {
                a0 += rr[i]     * sh_Wo[i * LL + tid];
                a1 += rr[i + 1] * sh_Wo[(i + 1) * LL + tid];
            }
            float acc = sh_bo[tid] + a0 + a1;
            out[OFF_SEQ + t * LL + tid] = fminf(fmaxf(acc, 0.0f), 1.0f);
        }
        // no barrier: next phase A reads only sh_r (stable until next J)
    }
}

extern "C" void kernel_launch(void* const* d_in, const int* in_sizes, int n_in,
                              void* d_out, int out_size, void* d_ws, size_t ws_size,
                              hipStream_t stream) {
    const float* seq = (const float*)d_in[0];
    const float* Wc  = (const float*)d_in[1];
    const float* bc  = (const float*)d_in[2];
    const float* Wr  = (const float*)d_in[3];
    const float* br  = (const float*)d_in[4];
    const float* Ww  = (const float*)d_in[5];
    const float* bw  = (const float*)d_in[6];
    const float* Wo  = (const float*)d_in[7];
    const float* bo  = (const float*)d_in[8];
    float* out = (float*)d_out;

    float* wsf  = (float*)d_ws;
    float* pre  = wsf + WSF_PRE;
    vf4*  ws_m  = (vf4*)(wsf + WSF_M);
    float* Wcat = wsf + WSF_WCAT;

    pre_kernel<<<(TT * CC) / 256, 256, 0, stream>>>(seq, Wc, bc, pre);
    pack_kernel<<<(512 * 272 + 255) / 256, 256, 0, stream>>>(Ww, Wr, Wcat);
    ntm_kernel<<<1, 1024, 0, stream>>>(pre, Wc, Wcat, br, bw, Wo, bo, out, ws_m);
}

// Round 9
// 183128.784 us; speedup vs baseline: 2.6586x; 2.6586x over previous
//
#include <hip/hip_runtime.h>
#include <math.h>

// Problem constants
#define NN 1024
#define MM 64
#define CC 512
#define LL 64
#define TT 8192
#define EPSF 1e-16f

// Flat output offsets (return order: seq_out, ww_h, rw_h, a_h, r_h)
#define OFF_SEQ 0
#define OFF_WW  (TT*LL)
#define OFF_RW  (OFF_WW + TT*NN)
#define OFF_A   (OFF_RW + TT*NN)
#define OFF_R   (OFF_A + TT*MM)

// d_ws float offsets
#define WSF_PRE   0
#define WSF_M     (TT*CC)              // 8*1024 float4 = 32768 floats (M cols 32..63)
#define WSF_WCAT  (WSF_M + 32768)      // 512*272 packed [Ww | Wr | 0pad]

__device__ __forceinline__ float sigmoid_f(float x) { return 1.0f / (1.0f + __expf(-x)); }
__device__ __forceinline__ float softplus_f(float x) { return (x > 15.0f) ? x : __logf(1.0f + __expf(x)); }
__device__ __forceinline__ float tanh_f(float x) { float e = __expf(2.0f * x); return 1.0f - 2.0f / (e + 1.0f); }
__device__ __forceinline__ float pow_f(float b, float g) { return __expf(g * __logf(b)); }  // b >= 0
__device__ __forceinline__ int bitrev4(int l) {
    return ((l & 1) << 3) | ((l & 2) << 1) | ((l & 4) >> 1) | ((l & 8) >> 3);
}

// Kernel 1: pre[t][j] = sum_i seq[t][i] * Wc[i][j] + bc[j]
__global__ void pre_kernel(const float* __restrict__ seq, const float* __restrict__ Wc,
                           const float* __restrict__ bc, float* __restrict__ pre) {
    int gid = blockIdx.x * blockDim.x + threadIdx.x;
    int t = gid >> 9;
    int j = gid & 511;
    if (t >= TT) return;
    const float* s = seq + t * LL;
    float acc = bc[j];
    #pragma unroll 8
    for (int i = 0; i < LL; ++i) acc += s[i] * Wc[i * CC + j];
    pre[gid] = acc;
}

// Kernel 1b: Wcat[512][272] = [Ww (198 cols) | Wr (70 cols) | 4 zero cols]
__global__ void pack_kernel(const float* __restrict__ Ww, const float* __restrict__ Wr,
                            float* __restrict__ Wcat) {
    int gid = blockIdx.x * 256 + threadIdx.x;
    if (gid >= 512 * 272) return;
    int r = gid / 272, c = gid - r * 272;
    float v = 0.0f;
    if (c < 198) v = Ww[r * 198 + c];
    else if (c < 268) v = Wr[r * 70 + (c - 198)];
    Wcat[gid] = v;
}

// Persistent single workgroup — round-7 verified structure (174 ms): M cols 0-31 in
// 32 VGPRs, cols 32-63 in ws_m float4 private slots; fp32 throughout; float4 weight
// loads (coalesced 16B/lane). Round-9 tweaks only:
//   (1) mh load hoisted from E to top of D -> L2 latency overlaps D + barrier 4.
//   (2) rw-store deferred J->K via sh_wpbuf stash -> no vmcnt drain at barrier 9.
// Round-8 lesson (reverted): LDS-cached weights (strided b128 -> 8-way bank conflicts)
// and runtime-bound loops (defeat unroll) cost 2.8x. Round-6 lesson: per-element LDS M
// is DS-pipe-bound. Keep bulk streams on L2, LDS only for small broadcast data.
__global__ __launch_bounds__(1024)
void ntm_kernel(
    const float* __restrict__ pre,   // [TT][CC]
    const float* __restrict__ Wc,    // [128][512]
    const float* __restrict__ Wcat,  // [512][272] packed Ww|Wr
    const float* __restrict__ br,    // [70]
    const float* __restrict__ bw,    // [198]
    const float* __restrict__ Wo,    // [64][64]
    const float* __restrict__ bo,    // [64]
    float* __restrict__ out,
    float4* __restrict__ ws_m)       // [8][1024] private M cols 32..63
{
    __shared__ __align__(16) float sh_part[4096];     // A: 8x512 ; C: 8x272
    __shared__ __align__(16) float sh_h[CC];
    __shared__ __align__(16) float sh_kw[MM];
    __shared__ __align__(16) float sh_kr[MM];
    __shared__ __align__(16) float sh_e[MM];
    __shared__ __align__(16) float sh_a[MM];
    __shared__ __align__(16) float sh_scal[16];
    __shared__ __align__(16) float sh_evbuf[NN];
    __shared__ __align__(16) float sh_wpbuf[NN];
    __shared__ __align__(16) float red[4][16];
    __shared__ __align__(16) float wmat[16][MM];
    __shared__ __align__(16) float sh_r[MM];
    __shared__ __align__(16) float sh_Wo[MM * LL];
    __shared__ __align__(16) float sh_bo[LL];
    __shared__ __align__(16) float sh_bw[200];
    __shared__ __align__(16) float sh_br[72];
    __shared__ __align__(16) float sh_pren[CC];       // prefetched pre[t+1]

    const int tid  = threadIdx.x;
    const int lane = tid & 63;
    const int wv   = tid >> 6;

    // ---- preload constants into LDS, init state ----
    for (int i = tid; i < MM * LL; i += NN) sh_Wo[i] = Wo[i];
    if (tid < LL)  sh_bo[tid] = bo[tid];
    if (tid < 198) sh_bw[tid] = bw[tid];
    if (tid < 70)  sh_br[tid] = br[tid];
    if (tid < MM)  sh_r[tid] = 1e-6f;
    if (tid < CC)  sh_pren[tid] = pre[tid];

    float Mlo[32];
    #pragma unroll
    for (int j = 0; j < 32; ++j) Mlo[j] = 1e-6f;
    float4 mh[8];
    #pragma unroll
    for (int k = 0; k < 8; ++k) {
        mh[k] = make_float4(1e-6f, 1e-6f, 1e-6f, 1e-6f);
        ws_m[k * NN + tid] = mh[k];
    }
    float rown = sqrtf(64.0f * 1e-12f);
    float wwprev = (tid == NN / 2) ? 1.0f : 0.0f;
    float rwprev = wwprev;
    __syncthreads();

    for (int t = 0; t < TT; ++t) {
        // ===== A: h-partials, float4 col-groups. thread=(g:128 col-groups, q:8 row-chunks) =====
        {
            int g = tid & 127, q = tid >> 7;          // cols 4g..4g+3, rows 8q..8q+7 of Wc2
            const float4* wbase = (const float4*)(Wc + (64 + q * 8) * CC) + g;
            float4 acc = make_float4(0.0f, 0.0f, 0.0f, 0.0f);
            #pragma unroll
            for (int i = 0; i < 8; ++i) {
                float rv = sh_r[q * 8 + i];
                float4 w = wbase[i * 128];            // next row: +512 floats = +128 float4
                acc.x += rv * w.x; acc.y += rv * w.y;
                acc.z += rv * w.z; acc.w += rv * w.w;
            }
            ((float4*)sh_part)[q * 128 + g] = acc;    // sh_part[q*512 + 4g]
        }
        __syncthreads();  // 1
        // ===== B: h = tanh(pre + 8 partials) =====
        if (tid < CC) {
            float p0 = sh_part[tid]          + sh_part[512 + tid];
            float p1 = sh_part[1024 + tid]   + sh_part[1536 + tid];
            float p2 = sh_part[2048 + tid]   + sh_part[2560 + tid];
            float p3 = sh_part[3072 + tid]   + sh_part[3584 + tid];
            float v = sh_pren[tid] + ((p0 + p1) + (p2 + p3));
            sh_h[tid] = tanh_f(v);
        }
        __syncthreads();  // 2
        // ===== C: ow/orr partials, float4 col-groups of Wcat. 544 threads =====
        if (tid < 544) {
            int g = tid % 68, q = tid / 68;           // cols 4g..4g+3, rows 64q..64q+63
            const float4* wbase = (const float4*)(Wcat + (q * 64) * 272) + g;
            float4 acc = make_float4(0.0f, 0.0f, 0.0f, 0.0f);
            #pragma unroll 8
            for (int i = 0; i < 64; ++i) {
                float hv = sh_h[q * 64 + i];
                float4 w = wbase[i * 68];             // next row: +272 floats = +68 float4
                acc.x += hv * w.x; acc.y += hv * w.y;
                acc.z += hv * w.z; acc.w += hv * w.w;
            }
            ((float4*)sh_part)[q * 68 + g] = acc;     // sh_part[q*272 + 4g]
        }
        __syncthreads();  // 3
        // ===== D: head transforms; mh prefetch issued first (covered by D + barrier 4) =====
        #pragma unroll
        for (int k = 0; k < 8; ++k) mh[k] = ws_m[k * NN + tid];
        #define OWV(c) ( (((sh_part[(c)] + sh_part[272 + (c)]) + (sh_part[544 + (c)] + sh_part[816 + (c)])) \
                        + ((sh_part[1088 + (c)] + sh_part[1360 + (c)]) + (sh_part[1632 + (c)] + sh_part[1904 + (c)]))) \
                        + ((c) < 198 ? sh_bw[(c)] : sh_br[(c) - 198]) )
        if (wv == 0) {
            float v = tanh_f(OWV(lane));
            sh_kw[lane] = v;
            float s2 = v * v;
            #pragma unroll
            for (int m = 1; m < 64; m <<= 1) s2 += __shfl_xor(s2, m, 64);
            if (lane == 0) sh_scal[6] = sqrtf(s2);
        } else if (wv == 1) {
            float v = tanh_f(OWV(198 + lane));
            sh_kr[lane] = v;
            float s2 = v * v;
            #pragma unroll
            for (int m = 1; m < 64; m <<= 1) s2 += __shfl_xor(s2, m, 64);
            if (lane == 0) sh_scal[14] = sqrtf(s2);
        } else if (wv == 2) {
            sh_e[lane] = sigmoid_f(OWV(70 + lane));
        } else if (wv == 3) {
            float v = tanh_f(OWV(134 + lane));
            sh_a[lane] = v;
            out[OFF_A + t * MM + lane] = v;
        } else if (wv == 4) {
            if (lane == 0) {
                sh_scal[0] = softplus_f(OWV(64));
                sh_scal[1] = sigmoid_f(OWV(65));
                float x0 = OWV(66), x1 = OWV(67), x2 = OWV(68);
                float mx = fmaxf(x0, fmaxf(x1, x2));
                float e0 = __expf(x0 - mx), e1 = __expf(x1 - mx), e2 = __expf(x2 - mx);
                float ss = e0 + e1 + e2;
                sh_scal[2] = e0 / ss; sh_scal[3] = e1 / ss; sh_scal[4] = e2 / ss;
                sh_scal[5] = 1.0f + softplus_f(OWV(69));
            }
        } else if (wv == 5) {
            if (lane == 0) {
                sh_scal[8] = softplus_f(OWV(198 + 64));
                sh_scal[9] = sigmoid_f(OWV(198 + 65));
                float x0 = OWV(198 + 66), x1 = OWV(198 + 67), x2 = OWV(198 + 68);
                float mx = fmaxf(x0, fmaxf(x1, x2));
                float e0 = __expf(x0 - mx), e1 = __expf(x1 - mx), e2 = __expf(x2 - mx);
                float ss = e0 + e1 + e2;
                sh_scal[10] = e0 / ss; sh_scal[11] = e1 / ss; sh_scal[12] = e2 / ss;
                sh_scal[13] = 1.0f + softplus_f(OWV(198 + 69));
            }
        } else if (wv >= 6 && wv < 14) {     // prefetch pre[t+1] into LDS (512 idle threads)
            if (t + 1 < TT) sh_pren[tid - 384] = pre[(t + 1) * CC + (tid - 384)];
        }
        #undef OWV
        __syncthreads();  // 4

        // ===== E: write-head dot + ev =====
        float betaW = sh_scal[0], gW = sh_scal[1];
        float s0W = sh_scal[2], s1W = sh_scal[3], s2W = sh_scal[4];
        float gamW = sh_scal[5], knW = sh_scal[6];
        {
            const float4* k4 = (const float4*)sh_kw;
            float d0 = 0.0f, d1 = 0.0f, d2 = 0.0f, d3 = 0.0f;
            #pragma unroll
            for (int j4 = 0; j4 < 8; ++j4) {
                float4 k = k4[j4];
                d0 += Mlo[4*j4]   * k.x;
                d1 += Mlo[4*j4+1] * k.y;
                d2 += Mlo[4*j4+2] * k.z;
                d3 += Mlo[4*j4+3] * k.w;
            }
            #pragma unroll
            for (int k8 = 0; k8 < 8; ++k8) {
                float4 k = k4[8 + k8];
                d0 += mh[k8].x * k.x;
                d1 += mh[k8].y * k.y;
                d2 += mh[k8].z * k.z;
                d3 += mh[k8].w * k.w;
            }
            float dot = (d0 + d1) + (d2 + d3);
            float sim = dot / (rown * knW + EPSF);
            float ev = __expf(betaW * sim);
            sh_evbuf[tid] = ev;
            sh_wpbuf[tid] = wwprev;
            float s = ev;
            #pragma unroll
            for (int m = 1; m < 64; m <<= 1) s += __shfl_xor(s, m, 64);
            if (lane == 0) red[0][wv] = s;
        }
        __syncthreads();  // 5
        // ===== F: conv + sharpen (write) =====
        float wshW;
        {
            const float4* rp = (const float4*)red[0];
            float Sev = 0.0f;
            #pragma unroll
            for (int w4 = 0; w4 < 4; ++w4) { float4 p = rp[w4]; Sev += p.x + p.y + p.z + p.w; }
            int tm1 = (tid + NN - 1) & (NN - 1), tp1 = (tid + 1) & (NN - 1);
            float cEV = s0W * sh_evbuf[tm1] + s1W * sh_evbuf[tid] + s2W * sh_evbuf[tp1];
            float cWP = s0W * sh_wpbuf[tm1] + s1W * sh_wpbuf[tid] + s2W * sh_wpbuf[tp1];
            float ws = (gW / Sev) * cEV + (1.0f - gW) * cWP;
            wshW = pow_f(ws, gamW);
            float s = wshW;
            #pragma unroll
            for (int m = 1; m < 64; m <<= 1) s += __shfl_xor(s, m, 64);
            if (lane == 0) red[1][wv] = s;
        }
        __syncthreads();  // 6
        // ===== G: normalize wwn; M update + norm =====
        {
            const float4* rp = (const float4*)red[1];
            float Swsh = 0.0f;
            #pragma unroll
            for (int w4 = 0; w4 < 4; ++w4) { float4 p = rp[w4]; Swsh += p.x + p.y + p.z + p.w; }
            float wwn = wshW / (Swsh + EPSF);
            out[OFF_WW + t * NN + tid] = wwn;
            wwprev = wwn;
            const float4* e4p = (const float4*)sh_e;
            const float4* a4p = (const float4*)sh_a;
            float n0 = 0.0f, n1 = 0.0f, n2 = 0.0f, n3 = 0.0f;
            #pragma unroll
            for (int j4 = 0; j4 < 8; ++j4) {
                float4 e = e4p[j4], a = a4p[j4];
                float m0 = Mlo[4*j4]   * (1.0f - wwn * e.x) + wwn * a.x;
                float m1 = Mlo[4*j4+1] * (1.0f - wwn * e.y) + wwn * a.y;
                float m2 = Mlo[4*j4+2] * (1.0f - wwn * e.z) + wwn * a.z;
                float m3 = Mlo[4*j4+3] * (1.0f - wwn * e.w) + wwn * a.w;
                Mlo[4*j4] = m0; Mlo[4*j4+1] = m1; Mlo[4*j4+2] = m2; Mlo[4*j4+3] = m3;
                n0 += m0 * m0; n1 += m1 * m1; n2 += m2 * m2; n3 += m3 * m3;
            }
            #pragma unroll
            for (int k = 0; k < 8; ++k) {
                float4 e = e4p[8 + k], a = a4p[8 + k];
                float4 m = mh[k];
                m.x = m.x * (1.0f - wwn * e.x) + wwn * a.x;
                m.y = m.y * (1.0f - wwn * e.y) + wwn * a.y;
                m.z = m.z * (1.0f - wwn * e.z) + wwn * a.z;
                m.w = m.w * (1.0f - wwn * e.w) + wwn * a.w;
                mh[k] = m;
                ws_m[k * NN + tid] = m;
                n0 += m.x * m.x; n1 += m.y * m.y; n2 += m.z * m.z; n3 += m.w * m.w;
            }
            rown = sqrtf((n0 + n1) + (n2 + n3));
        }

        // ===== H: read-head dot + ev =====
        float betaR = sh_scal[8], gR = sh_scal[9];
        float s0R = sh_scal[10], s1R = sh_scal[11], s2R = sh_scal[12];
        float gamR = sh_scal[13], knR = sh_scal[14];
        {
            const float4* k4 = (const float4*)sh_kr;
            float d0 = 0.0f, d1 = 0.0f, d2 = 0.0f, d3 = 0.0f;
            #pragma unroll
            for (int j4 = 0; j4 < 8; ++j4) {
                float4 k = k4[j4];
                d0 += Mlo[4*j4]   * k.x;
                d1 += Mlo[4*j4+1] * k.y;
                d2 += Mlo[4*j4+2] * k.z;
                d3 += Mlo[4*j4+3] * k.w;
            }
            #pragma unroll
            for (int k8 = 0; k8 < 8; ++k8) {
                float4 k = k4[8 + k8];
                d0 += mh[k8].x * k.x;
                d1 += mh[k8].y * k.y;
                d2 += mh[k8].z * k.z;
                d3 += mh[k8].w * k.w;
            }
            float dot = (d0 + d1) + (d2 + d3);
            float sim = dot / (rown * knR + EPSF);
            float ev = __expf(betaR * sim);
            sh_evbuf[tid] = ev;
            sh_wpbuf[tid] = rwprev;
            float s = ev;
            #pragma unroll
            for (int m = 1; m < 64; m <<= 1) s += __shfl_xor(s, m, 64);
            if (lane == 0) red[2][wv] = s;
        }
        __syncthreads();  // 7
        // ===== I: conv + sharpen (read); transpose partials =====
        float wshR;
        {
            const float4* rp = (const float4*)red[2];
            float Sev = 0.0f;
            #pragma unroll
            for (int w4 = 0; w4 < 4; ++w4) { float4 p = rp[w4]; Sev += p.x + p.y + p.z + p.w; }
            int tm1 = (tid + NN - 1) & (NN - 1), tp1 = (tid + 1) & (NN - 1);
            float cEV = s0R * sh_evbuf[tm1] + s1R * sh_evbuf[tid] + s2R * sh_evbuf[tp1];
            float cWP = s0R * sh_wpbuf[tm1] + s1R * sh_wpbuf[tid] + s2R * sh_wpbuf[tp1];
            float ws = (gR / Sev) * cEV + (1.0f - gR) * cWP;
            wshR = pow_f(ws, gamR);
            float s = wshR;
            #pragma unroll
            for (int m = 1; m < 64; m <<= 1) s += __shfl_xor(s, m, 64);
            if (lane == 0) red[3][wv] = s;
            #pragma unroll
            for (int chunk = 0; chunk < 4; ++chunk) {
                const int cb = chunk * 16;
                float v[16];
                if (chunk < 2) {
                    #pragma unroll
                    for (int i = 0; i < 16; ++i) v[i] = wshR * Mlo[chunk * 16 + i];
                } else {
                    #pragma unroll
                    for (int k = 0; k < 4; ++k) {
                        float4 m = mh[(chunk - 2) * 4 + k];
                        v[4*k]   = wshR * m.x;
                        v[4*k+1] = wshR * m.y;
                        v[4*k+2] = wshR * m.z;
                        v[4*k+3] = wshR * m.w;
                    }
                }
                #pragma unroll
                for (int st = 0; st < 4; ++st) {
                    const int m = 1 << st;
                    const int hs = 8 >> st;
                    bool hi = (lane & m) != 0;
                    #pragma unroll
                    for (int i = 0; i < 8; ++i) {
                        if (i < hs) {
                            float send = hi ? v[i] : v[i + hs];
                            float recv = __shfl_xor(send, m, 64);
                            float keep = hi ? v[i + hs] : v[i];
                            v[i] = keep + recv;
                        }
                    }
                }
                float v0 = v[0];
                v0 += __shfl_xor(v0, 16, 64);
                v0 += __shfl_xor(v0, 32, 64);
                if (lane < 16) wmat[wv][cb + bitrev4(lane)] = v0;
            }
        }
        __syncthreads();  // 8
        // ===== J: normalize rwn; stash rw in LDS (store deferred to K) =====
        {
            const float4* rp = (const float4*)red[3];
            float Swsh = 0.0f;
            #pragma unroll
            for (int w4 = 0; w4 < 4; ++w4) { float4 p = rp[w4]; Swsh += p.x + p.y + p.z + p.w; }
            float inv = 1.0f / (Swsh + EPSF);
            float rwn = wshR * inv;
            sh_wpbuf[tid] = rwn;          // deferred store: K writes it under phase-A cover
            rwprev = rwn;
            if (tid < MM) {
                float rv = 0.0f;
                #pragma unroll
                for (int w = 0; w < 16; ++w) rv += wmat[w][tid];
                rv *= inv;
                sh_r[tid] = rv;
                out[OFF_R + t * MM + tid] = rv;
            }
        }
        __syncthreads();  // 9
        // ===== K: deferred rw store + output projection =====
        out[OFF_RW + t * NN + tid] = sh_wpbuf[tid];
        if (tid < LL) {
            const float4* r4p = (const float4*)sh_r;
            float a0 = 0.0f, a1 = 0.0f;
            #pragma unroll
            for (int i4 = 0; i4 < 16; ++i4) {
                float4 r = r4p[i4];
                a0 += r.x * sh_Wo[(4*i4) * LL + tid]   + r.y * sh_Wo[(4*i4+1) * LL + tid];
                a1 += r.z * sh_Wo[(4*i4+2) * LL + tid] + r.w * sh_Wo[(4*i4+3) * LL + tid];
            }
            float acc = sh_bo[tid] + a0 + a1;
            out[OFF_SEQ + t * LL + tid] = fminf(fmaxf(acc, 0.0f), 1.0f);
        }
        // no barrier: next phase A reads only sh_r (stable until next J);
        // sh_wpbuf next written in E (barrier-separated from this read).
    }
}

extern "C" void kernel_launch(void* const* d_in, const int* in_sizes, int n_in,
                              void* d_out, int out_size, void* d_ws, size_t ws_size,
                              hipStream_t stream) {
    const float* seq = (const float*)d_in[0];
    const float* Wc  = (const float*)d_in[1];
    const float* bc  = (const float*)d_in[2];
    const float* Wr  = (const float*)d_in[3];
    const float* br  = (const float*)d_in[4];
    const float* Ww  = (const float*)d_in[5];
    const float* bw  = (const float*)d_in[6];
    const float* Wo  = (const float*)d_in[7];
    const float* bo  = (const float*)d_in[8];
    float* out = (float*)d_out;

    float* wsf  = (float*)d_ws;
    float* pre  = wsf + WSF_PRE;
    float4* ws_m = (float4*)(wsf + WSF_M);
    float* Wcat = wsf + WSF_WCAT;

    pre_kernel<<<(TT * CC) / 256, 256, 0, stream>>>(seq, Wc, bc, pre);
    pack_kernel<<<(512 * 272 + 255) / 256, 256, 0, stream>>>(Ww, Wr, Wcat);
    ntm_kernel<<<1, 1024, 0, stream>>>(pre, Wc, Wcat, br, bw, Wo, bo, out, ws_m);
}